// Round 3
// baseline (252.001 us; speedup 1.0000x reference)
//
#include <hip/hip_runtime.h>
#include <math.h>

// Beam search (8, 512, 32000) fp32, K=3 beams, T=5 top tokens.
// d_out is FLOAT32: tokens (8*512*3) then scores (8*3), concatenated flat.
// Stage 1: per-row (4096 rows) softmax denom + top-5 -> ws.
// Stage 2: per-batch sequential beam scan (frontier-pruned top-3 of 3x5) +
//          parallel backpointer suffix-composition for token reconstruction.

#define NB 8
#define NL 512
#define NV 32000
#define NT 5
#define NK 3
#define NEG_INF (-__builtin_inff())

typedef unsigned long long ull;

// Monotone sortable key: larger value wins; ties -> smaller flat index wins.
__device__ __forceinline__ ull make_key(float v, int flat) {
  unsigned u = __float_as_uint(v);
  unsigned m = u ^ ((unsigned)((int)u >> 31) | 0x80000000u);
  return ((ull)m << 8) | (ull)(15 - flat);
}

// maps {0,1,2}->{0,1,2} packed 2 bits each; h = f(g(x)) (g applied first)
__device__ __forceinline__ int compose_map(int f, int g) {
  int h0 = (f >> (2 * (g & 3))) & 3;
  int h1 = (f >> (2 * ((g >> 2) & 3))) & 3;
  int h2 = (f >> (2 * ((g >> 4) & 3))) & 3;
  return h0 | (h1 << 2) | (h2 << 4);
}

// ---------------- Kernel 1: per-(b,l) row: softmax denom + top-5 --------------
__global__ __launch_bounds__(256) void k_rowtop5(const float* __restrict__ logits,
                                                 float* __restrict__ lp_out,
                                                 int* __restrict__ idx_out) {
  __shared__ float sv[256 * 5];
  __shared__ int si[256 * 5];
  __shared__ double wsum[4];

  const int row = blockIdx.x;
  const int tid = threadIdx.x;
  const int lane = tid & 63;
  const int wv = tid >> 6;

  const float4* __restrict__ x4 = (const float4*)(logits + (size_t)row * NV);

  float tv0 = NEG_INF, tv1 = NEG_INF, tv2 = NEG_INF, tv3 = NEG_INF, tv4 = NEG_INF;
  int ti0 = 0, ti1 = 0, ti2 = 0, ti3 = 0, ti4 = 0;
  double sum = 0.0;

  // strict '>' keeps earlier (smaller) index first among equal values (stable,
  // matching lax.top_k), since each thread scans its indices in ascending order.
#define PROC(VAL, IDX)                                                         \
  {                                                                            \
    float val_ = (VAL);                                                        \
    sum += (double)__expf(val_ - 4.0f);                                        \
    if (val_ > tv4) {                                                          \
      int idx_ = (IDX);                                                        \
      if (val_ > tv2) {                                                        \
        if (val_ > tv1) {                                                      \
          if (val_ > tv0) {                                                    \
            tv4 = tv3; ti4 = ti3; tv3 = tv2; ti3 = ti2; tv2 = tv1; ti2 = ti1;  \
            tv1 = tv0; ti1 = ti0; tv0 = val_; ti0 = idx_;                      \
          } else {                                                             \
            tv4 = tv3; ti4 = ti3; tv3 = tv2; ti3 = ti2; tv2 = tv1; ti2 = ti1;  \
            tv1 = val_; ti1 = idx_;                                            \
          }                                                                    \
        } else {                                                               \
          tv4 = tv3; ti4 = ti3; tv3 = tv2; ti3 = ti2; tv2 = val_; ti2 = idx_;  \
        }                                                                      \
      } else {                                                                 \
        if (val_ > tv3) { tv4 = tv3; ti4 = ti3; tv3 = val_; ti3 = idx_; }      \
        else { tv4 = val_; ti4 = idx_; }                                       \
      }                                                                        \
    }                                                                          \
  }

  for (int v = tid; v < NV / 4; v += 256) {
    float4 f = x4[v];
    int base = v * 4;
    PROC(f.x, base + 0);
    PROC(f.y, base + 1);
    PROC(f.z, base + 2);
    PROC(f.w, base + 3);
  }
#undef PROC

  // block sum of exp(x-4), double accumulation
#pragma unroll
  for (int d = 1; d < 64; d <<= 1) sum += __shfl_xor(sum, d);
  if (lane == 0) wsum[wv] = sum;

  sv[tid * 5 + 0] = tv0; si[tid * 5 + 0] = ti0;
  sv[tid * 5 + 1] = tv1; si[tid * 5 + 1] = ti1;
  sv[tid * 5 + 2] = tv2; si[tid * 5 + 2] = ti2;
  sv[tid * 5 + 3] = tv3; si[tid * 5 + 3] = ti3;
  sv[tid * 5 + 4] = tv4; si[tid * 5 + 4] = ti4;
  __syncthreads();
  if (wv != 0) return;  // wave 0 finishes alone; no further barriers

  const double S = wsum[0] + wsum[1] + wsum[2] + wsum[3];

  // each lane of wave 0 merges the sorted lists of threads 4*lane..4*lane+3
  const int b0 = (4 * lane + 0) * 5;
  const int b1 = (4 * lane + 1) * 5;
  const int b2 = (4 * lane + 2) * 5;
  const int b3 = (4 * lane + 3) * 5;
  int h0 = 0, h1 = 0, h2 = 0, h3 = 0;
  float mv[5]; int mi[5];
#pragma unroll
  for (int k = 0; k < 5; ++k) {
    float v0 = (h0 < 5) ? sv[b0 + h0] : NEG_INF; int j0 = (h0 < 5) ? si[b0 + h0] : 0x7fffffff;
    float v1 = (h1 < 5) ? sv[b1 + h1] : NEG_INF; int j1 = (h1 < 5) ? si[b1 + h1] : 0x7fffffff;
    float v2 = (h2 < 5) ? sv[b2 + h2] : NEG_INF; int j2 = (h2 < 5) ? si[b2 + h2] : 0x7fffffff;
    float v3 = (h3 < 5) ? sv[b3 + h3] : NEG_INF; int j3 = (h3 < 5) ? si[b3 + h3] : 0x7fffffff;
    float bv = v0; int bj = j0; int bs = 0;
    if (v1 > bv || (v1 == bv && j1 < bj)) { bv = v1; bj = j1; bs = 1; }
    if (v2 > bv || (v2 == bv && j2 < bj)) { bv = v2; bj = j2; bs = 2; }
    if (v3 > bv || (v3 == bv && j3 < bj)) { bv = v3; bj = j3; bs = 3; }
    mv[k] = bv; mi[k] = bj;
    h0 += (bs == 0); h1 += (bs == 1); h2 += (bs == 2); h3 += (bs == 3);
  }

  // 5 rounds of wave-wide argmax-pop (ties -> smaller index; indices unique)
  float outv = 0.f; int outi = 0;
#pragma unroll
  for (int it = 0; it < 5; ++it) {
    float v = mv[0]; int i = mi[0];
#pragma unroll
    for (int d = 1; d < 64; d <<= 1) {
      float ov = __shfl_xor(v, d); int oi = __shfl_xor(i, d);
      if (ov > v || (ov == v && oi < i)) { v = ov; i = oi; }
    }
    if (i == mi[0]) {  // unique winner pops its head
      mv[0] = mv[1]; mi[0] = mi[1];
      mv[1] = mv[2]; mi[1] = mi[2];
      mv[2] = mv[3]; mi[2] = mi[3];
      mv[3] = mv[4]; mi[3] = mi[4];
      mv[4] = NEG_INF; mi[4] = 0x7fffffff;
    }
    if (lane == it) { outv = v; outi = i; }
  }

  if (lane < 5) {
    // near-correctly-rounded lp: double exp / double S / double log -> fp32
    double p = exp((double)outv - 4.0) / S;
    float lp = (float)log(p + 2.220446049250313e-16);
    lp_out[row * 5 + lane] = lp;
    idx_out[row * 5 + lane] = outi;
  }
}

// ---------------- Kernel 2: per-batch beam scan + backtrace -------------------
// Frontier pruning (rows: beams desc, cols: lp desc):
//   top-1 = c00 always; c11 dominated by c01 (flat 1<6), c10 (5<6), c00
//   -> never top-3. Only {c00,c01,c02,c10,c20} can place.
//   t1 = max(c01,c10); t1==c01 -> t2 = max(c02,c10); else t2 = max(c01,c20).
__global__ __launch_bounds__(64) void k_beamscan(const float* __restrict__ lp_in,
                                                 const int* __restrict__ idx_in,
                                                 float* __restrict__ out) {
  __shared__ float lpL[NL * NT];
  __shared__ int idxL[NL * NT];
  __shared__ int tokpar[NL * NK];  // token | parent<<20

  const int b = blockIdx.x;
  const int tid = threadIdx.x;

  for (int i = tid; i < NL * NT; i += 64) {
    lpL[i] = lp_in[(size_t)b * NL * NT + i];
    idxL[i] = idx_in[(size_t)b * NL * NT + i];
  }
  __syncthreads();

  if (tid == 0) {
    float s0 = 0.f, s1 = NEG_INF, s2 = NEG_INF;
    float l0 = lpL[0], l1 = lpL[1], l2 = lpL[2];
    for (int t = 0; t < NL; ++t) {
      float n0 = 0.f, n1 = 0.f, n2 = 0.f;  // prefetch next step's lp
      if (t + 1 < NL) {
        n0 = lpL[(t + 1) * NT + 0];
        n1 = lpL[(t + 1) * NT + 1];
        n2 = lpL[(t + 1) * NT + 2];
      }
      float c00 = s0 + l0, c01 = s0 + l1, c02 = s0 + l2;
      float c10 = s1 + l0, c20 = s2 + l0;
      ull K01 = make_key(c01, 1), K02 = make_key(c02, 2);
      ull K10 = make_key(c10, 5), K20 = make_key(c20, 10);
      bool a = K01 > K10;
      ull t1k = a ? K01 : K10; float t1v = a ? c01 : c10;
      ull alk = a ? K02 : K20; float alv = a ? c02 : c20;
      ull otk = a ? K10 : K01; float otv = a ? c10 : c01;
      bool sel2 = otk > alk;
      ull t2k = sel2 ? otk : alk; float t2v = sel2 ? otv : alv;
      int f1 = 15 - (int)(t1k & 0xFFull);
      int f2 = 15 - (int)(t2k & 0xFFull);
      int p1 = f1 / 5, q1 = f1 - p1 * 5;
      int p2 = f2 / 5, q2 = f2 - p2 * 5;
      tokpar[t * 3 + 0] = idxL[t * NT + 0];  // parent 0
      tokpar[t * 3 + 1] = idxL[t * NT + q1] | (p1 << 20);
      tokpar[t * 3 + 2] = idxL[t * NT + q2] | (p2 << 20);
      s0 = c00; s1 = t1v; s2 = t2v;
      l0 = n0; l1 = n1; l2 = n2;
    }
    // scores output as float32
    out[NB * NL * NK + b * NK + 0] = s0;
    out[NB * NL * NK + b * NK + 1] = s1;
    out[NB * NL * NK + b * NK + 2] = s2;
  }
  __syncthreads();

  // parallel backtrace: suffix composition of parent maps g_t over t
  const int ID3 = 0 | (1 << 2) | (2 << 4);
  const int base = tid * 8;
  int P = ID3;
#pragma unroll
  for (int k = 7; k >= 0; --k) {  // local product, highest t applied first
    int t = base + k;
    int g = (tokpar[t * 3 + 0] >> 20) | ((tokpar[t * 3 + 1] >> 20) << 2) |
            ((tokpar[t * 3 + 2] >> 20) << 4);
    P = compose_map(g, P);
  }
  int X = P;  // inclusive suffix scan across lanes
#pragma unroll
  for (int d = 1; d < 64; d <<= 1) {
    int o = __shfl_down(X, d);
    if (tid + d < 64) X = compose_map(X, o);
  }
  int E = __shfl_down(X, 1);  // exclusive suffix = composition over t > base+7
  if (tid == 63) E = ID3;

  int R = E;  // map_t for t = base+7
  const int ob = b * NL * NK;
#pragma unroll
  for (int k = 7; k >= 0; --k) {
    int t = base + k;
    int e0 = tokpar[t * 3 + 0];
    int e1 = tokpar[t * 3 + 1];
    int e2 = tokpar[t * 3 + 2];
    int m0 = R & 3, m1 = (R >> 2) & 3, m2 = (R >> 4) & 3;
    int tok0 = (m0 == 0 ? e0 : m0 == 1 ? e1 : e2) & 0xFFFFF;
    int tok1 = (m1 == 0 ? e0 : m1 == 1 ? e1 : e2) & 0xFFFFF;
    int tok2 = (m2 == 0 ? e0 : m2 == 1 ? e1 : e2) & 0xFFFFF;
    out[ob + t * 3 + 0] = (float)tok0;
    out[ob + t * 3 + 1] = (float)tok1;
    out[ob + t * 3 + 2] = (float)tok2;
    int g = (e0 >> 20) | ((e1 >> 20) << 2) | ((e2 >> 20) << 4);
    R = compose_map(g, R);
  }
}

extern "C" void kernel_launch(void* const* d_in, const int* in_sizes, int n_in,
                              void* d_out, int out_size, void* d_ws, size_t ws_size,
                              hipStream_t stream) {
  const float* logits = (const float*)d_in[0];
  float* lp = (float*)d_ws;
  int* idx = (int*)((char*)d_ws + (size_t)NB * NL * NT * sizeof(float));
  float* out = (float*)d_out;

  hipLaunchKernelGGL(k_rowtop5, dim3(NB * NL), dim3(256), 0, stream, logits, lp, idx);
  hipLaunchKernelGGL(k_beamscan, dim3(NB), dim3(64), 0, stream, lp, idx, out);
}

// Round 4
// 152.923 us; speedup vs baseline: 1.6479x; 1.6479x over previous
//
#include <hip/hip_runtime.h>
#include <math.h>

// Beam search (8, 512, 32000) fp32, K=3 beams, T=5 top tokens.
// d_out is FLOAT32: tokens (8*512*3) then scores (8*3), concatenated flat.
// Stage 1: per-row (4096 rows) softmax denom + top-5 -> ws (branch-free insert).
// Stage 2: per-batch serial score scan (2 decision bits/step) + parallel token
//          reconstruction + backpointer suffix-composition.

#define NB 8
#define NL 512
#define NV 32000
#define NT 5
#define NK 3
#define NEG_INF (-__builtin_inff())

// maps {0,1,2}->{0,1,2} packed 2 bits each; h = f(g(x)) (g applied first)
__device__ __forceinline__ int compose_map(int f, int g) {
  int h0 = (f >> (2 * (g & 3))) & 3;
  int h1 = (f >> (2 * ((g >> 2) & 3))) & 3;
  int h2 = (f >> (2 * ((g >> 4) & 3))) & 3;
  return h0 | (h1 << 2) | (h2 << 4);
}

// ---------------- Kernel 1: per-(b,l) row: softmax denom + top-5 --------------
__global__ __launch_bounds__(256) void k_rowtop5(const float* __restrict__ logits,
                                                 float* __restrict__ lp_out,
                                                 int* __restrict__ idx_out) {
  __shared__ float sv[256 * 5];
  __shared__ int si[256 * 5];
  __shared__ double wsum[4];

  const int row = blockIdx.x;
  const int tid = threadIdx.x;
  const int lane = tid & 63;
  const int wv = tid >> 6;

  const float4* __restrict__ x4 = (const float4*)(logits + (size_t)row * NV);

  float tv0 = NEG_INF, tv1 = NEG_INF, tv2 = NEG_INF, tv3 = NEG_INF, tv4 = NEG_INF;
  int ti0 = 0, ti1 = 0, ti2 = 0, ti3 = 0, ti4 = 0;
  double sum = 0.0;

  // Branch-free sorted-desc insert. Strict '>' keeps earlier (smaller) index
  // ranked first among equal values (stable, matching lax.top_k) since each
  // thread scans its indices in ascending order. Update order 4->0 so each
  // level reads the OLD value of the level above.
#define PROC(VAL, IDX)                                                         \
  {                                                                            \
    float val_ = (VAL);                                                        \
    int idx_ = (IDX);                                                          \
    sum += (double)__expf(val_ - 4.0f);                                        \
    bool b0_ = val_ > tv0, b1_ = val_ > tv1, b2_ = val_ > tv2;                 \
    bool b3_ = val_ > tv3, b4_ = val_ > tv4;                                   \
    tv4 = b4_ ? (b3_ ? tv3 : val_) : tv4; ti4 = b4_ ? (b3_ ? ti3 : idx_) : ti4;\
    tv3 = b3_ ? (b2_ ? tv2 : val_) : tv3; ti3 = b3_ ? (b2_ ? ti2 : idx_) : ti3;\
    tv2 = b2_ ? (b1_ ? tv1 : val_) : tv2; ti2 = b2_ ? (b1_ ? ti1 : idx_) : ti2;\
    tv1 = b1_ ? (b0_ ? tv0 : val_) : tv1; ti1 = b1_ ? (b0_ ? ti0 : idx_) : ti1;\
    tv0 = b0_ ? val_ : tv0;               ti0 = b0_ ? idx_ : ti0;              \
  }

  for (int v = tid; v < NV / 4; v += 256) {
    float4 f = x4[v];
    int base = v * 4;
    PROC(f.x, base + 0);
    PROC(f.y, base + 1);
    PROC(f.z, base + 2);
    PROC(f.w, base + 3);
  }
#undef PROC

  // block sum of exp(x-4), double accumulation
#pragma unroll
  for (int d = 1; d < 64; d <<= 1) sum += __shfl_xor(sum, d);
  if (lane == 0) wsum[wv] = sum;

  sv[tid * 5 + 0] = tv0; si[tid * 5 + 0] = ti0;
  sv[tid * 5 + 1] = tv1; si[tid * 5 + 1] = ti1;
  sv[tid * 5 + 2] = tv2; si[tid * 5 + 2] = ti2;
  sv[tid * 5 + 3] = tv3; si[tid * 5 + 3] = ti3;
  sv[tid * 5 + 4] = tv4; si[tid * 5 + 4] = ti4;
  __syncthreads();
  if (wv != 0) return;  // wave 0 finishes alone; no further barriers

  const double S = wsum[0] + wsum[1] + wsum[2] + wsum[3];

  // each lane of wave 0 merges the sorted lists of threads 4*lane..4*lane+3
  const int b0 = (4 * lane + 0) * 5;
  const int b1 = (4 * lane + 1) * 5;
  const int b2 = (4 * lane + 2) * 5;
  const int b3 = (4 * lane + 3) * 5;
  int h0 = 0, h1 = 0, h2 = 0, h3 = 0;
  float mv[5]; int mi[5];
#pragma unroll
  for (int k = 0; k < 5; ++k) {
    float v0 = (h0 < 5) ? sv[b0 + h0] : NEG_INF; int j0 = (h0 < 5) ? si[b0 + h0] : 0x7fffffff;
    float v1 = (h1 < 5) ? sv[b1 + h1] : NEG_INF; int j1 = (h1 < 5) ? si[b1 + h1] : 0x7fffffff;
    float v2 = (h2 < 5) ? sv[b2 + h2] : NEG_INF; int j2 = (h2 < 5) ? si[b2 + h2] : 0x7fffffff;
    float v3 = (h3 < 5) ? sv[b3 + h3] : NEG_INF; int j3 = (h3 < 5) ? si[b3 + h3] : 0x7fffffff;
    float bv = v0; int bj = j0; int bs = 0;
    if (v1 > bv || (v1 == bv && j1 < bj)) { bv = v1; bj = j1; bs = 1; }
    if (v2 > bv || (v2 == bv && j2 < bj)) { bv = v2; bj = j2; bs = 2; }
    if (v3 > bv || (v3 == bv && j3 < bj)) { bv = v3; bj = j3; bs = 3; }
    mv[k] = bv; mi[k] = bj;
    h0 += (bs == 0); h1 += (bs == 1); h2 += (bs == 2); h3 += (bs == 3);
  }

  // 5 rounds of wave-wide argmax-pop (ties -> smaller index; indices unique)
  float outv = 0.f; int outi = 0;
#pragma unroll
  for (int it = 0; it < 5; ++it) {
    float v = mv[0]; int i = mi[0];
#pragma unroll
    for (int d = 1; d < 64; d <<= 1) {
      float ov = __shfl_xor(v, d); int oi = __shfl_xor(i, d);
      if (ov > v || (ov == v && oi < i)) { v = ov; i = oi; }
    }
    if (i == mi[0]) {  // unique winner pops its head
      mv[0] = mv[1]; mi[0] = mi[1];
      mv[1] = mv[2]; mi[1] = mi[2];
      mv[2] = mv[3]; mi[2] = mi[3];
      mv[3] = mv[4]; mi[3] = mi[4];
      mv[4] = NEG_INF; mi[4] = 0x7fffffff;
    }
    if (lane == it) { outv = v; outi = i; }
  }

  if (lane < 5) {
    // near-correctly-rounded lp: double exp / double S / double log -> fp32
    double p = exp((double)outv - 4.0) / S;
    float lp = (float)log(p + 2.220446049250313e-16);
    lp_out[row * 5 + lane] = lp;
    idx_out[row * 5 + lane] = outi;
  }
}

// ---------------- Kernel 2: per-batch beam scan + backtrace -------------------
// Frontier pruning (rows: beams desc s0>=s1>=s2, cols: lp desc l0>=l1>=l2):
//   cell (k,t) has (k+1)(t+1)-1 strict-rank dominators -> only
//   {c00,c01,c02,c10,c20} can reach top-3. top1 = c00 always.
//   t1 = better(c01[flat1], c10[flat5]); if t1==c01: t2 = better(c02[2],c10[5])
//   else t2 = better(c01[1], c20[10]). In each compare the left operand has the
//   smaller flat index, so float '>=' reproduces top_k tie-breaking exactly.
__global__ __launch_bounds__(64) void k_beamscan(const float* __restrict__ lp_in,
                                                 const int* __restrict__ idx_in,
                                                 float* __restrict__ out) {
  __shared__ float lpc[(NL + 8) * 3];       // compacted l0,l1,l2 per step + pad
  __shared__ int idxL[NL * NT];
  __shared__ unsigned char selb[NL / 4];    // 2 decision bits per step

  const int b = blockIdx.x;
  const int tid = threadIdx.x;

  // stage idx (vectorized) and compacted lp triples
  const int4* ip = (const int4*)(idx_in + (size_t)b * NL * NT);
  for (int i = tid; i < NL * NT / 4; i += 64) ((int4*)idxL)[i] = ip[i];
  const float* lpb = lp_in + (size_t)b * NL * NT;
  for (int i = tid; i < NL; i += 64) {
    lpc[i * 3 + 0] = lpb[i * 5 + 0];
    lpc[i * 3 + 1] = lpb[i * 5 + 1];
    lpc[i * 3 + 2] = lpb[i * 5 + 2];
  }
  if (tid < 24) lpc[NL * 3 + tid] = 0.f;  // prefetch overrun pad
  __syncthreads();

  if (tid == 0) {
    float s0 = 0.f, s1 = NEG_INF, s2 = NEG_INF;
    float lA0 = lpc[0], lA1 = lpc[1],  lA2 = lpc[2];
    float lB0 = lpc[3], lB1 = lpc[4],  lB2 = lpc[5];
    float lC0 = lpc[6], lC1 = lpc[7],  lC2 = lpc[8];
    float lD0 = lpc[9], lD1 = lpc[10], lD2 = lpc[11];
    for (int t = 0; t < NL; t += 4) {
      unsigned byte_ = 0;
      int pfb = (t + 4) * 3;
#define STEP(L0, L1, L2, SH, PF)                                               \
      {                                                                        \
        float c00 = s0 + L0, c01 = s0 + L1, c02 = s0 + L2;                     \
        float c10 = s1 + L0, c20 = s2 + L0;                                    \
        bool a_ = c01 >= c10;                                                  \
        float xv = a_ ? c02 : c01;                                             \
        float yv = a_ ? c10 : c20;                                             \
        bool sb_ = xv >= yv;                                                   \
        s0 = c00;                                                              \
        s1 = a_ ? c01 : c10;                                                   \
        s2 = sb_ ? xv : yv;                                                    \
        byte_ |= ((unsigned)a_ | ((unsigned)sb_ << 1)) << (SH);                \
        PF                                                                     \
      }
      STEP(lA0, lA1, lA2, 0, { lA0 = lpc[pfb + 0]; lA1 = lpc[pfb + 1];  lA2 = lpc[pfb + 2]; })
      STEP(lB0, lB1, lB2, 2, { lB0 = lpc[pfb + 3]; lB1 = lpc[pfb + 4];  lB2 = lpc[pfb + 5]; })
      STEP(lC0, lC1, lC2, 4, { lC0 = lpc[pfb + 6]; lC1 = lpc[pfb + 7];  lC2 = lpc[pfb + 8]; })
      STEP(lD0, lD1, lD2, 6, { lD0 = lpc[pfb + 9]; lD1 = lpc[pfb + 10]; lD2 = lpc[pfb + 11]; })
#undef STEP
      selb[t >> 2] = (unsigned char)byte_;
    }
    out[NB * NL * NK + b * NK + 0] = s0;
    out[NB * NL * NK + b * NK + 1] = s1;
    out[NB * NL * NK + b * NK + 2] = s2;
  }
  __syncthreads();

  // decode this lane's 8 steps: tokens + parents from decision bits
  const int base = tid * 8;
  unsigned bits0 = selb[(base >> 2) + 0];
  unsigned bits1 = selb[(base >> 2) + 1];
  int e0[8], e1[8], e2[8];  // token | parent<<20
#pragma unroll
  for (int k = 0; k < 8; ++k) {
    int t = base + k;
    unsigned bb = ((k < 4) ? (bits0 >> (2 * k)) : (bits1 >> (2 * (k - 4)))) & 3u;
    int a_ = bb & 1, sb_ = (bb >> 1) & 1;
    int q1 = a_ ? 1 : 0, p1 = a_ ? 0 : 1;
    int q2 = a_ ? (sb_ ? 2 : 0) : (sb_ ? 1 : 0);
    int p2 = a_ ? (sb_ ? 0 : 1) : (sb_ ? 0 : 2);
    e0[k] = idxL[t * NT + 0];
    e1[k] = idxL[t * NT + q1] | (p1 << 20);
    e2[k] = idxL[t * NT + q2] | (p2 << 20);
  }

  // parallel backtrace: suffix composition of parent maps g_t over t
  const int ID3 = 0 | (1 << 2) | (2 << 4);
  int P = ID3;
#pragma unroll
  for (int k = 7; k >= 0; --k) {  // local product, highest t applied first
    int g = (e0[k] >> 20) | ((e1[k] >> 20) << 2) | ((e2[k] >> 20) << 4);
    P = compose_map(g, P);
  }
  int X = P;  // inclusive suffix scan across lanes
#pragma unroll
  for (int d = 1; d < 64; d <<= 1) {
    int o = __shfl_down(X, d);
    if (tid + d < 64) X = compose_map(X, o);
  }
  int E = __shfl_down(X, 1);  // exclusive suffix = composition over t > base+7
  if (tid == 63) E = ID3;

  int R = E;  // map_t for t = base+7
  const int ob = b * NL * NK;
#pragma unroll
  for (int k = 7; k >= 0; --k) {
    int t = base + k;
    int m0 = R & 3, m1 = (R >> 2) & 3, m2 = (R >> 4) & 3;
    int tok0 = (m0 == 0 ? e0[k] : m0 == 1 ? e1[k] : e2[k]) & 0xFFFFF;
    int tok1 = (m1 == 0 ? e0[k] : m1 == 1 ? e1[k] : e2[k]) & 0xFFFFF;
    int tok2 = (m2 == 0 ? e0[k] : m2 == 1 ? e1[k] : e2[k]) & 0xFFFFF;
    out[ob + t * 3 + 0] = (float)tok0;
    out[ob + t * 3 + 1] = (float)tok1;
    out[ob + t * 3 + 2] = (float)tok2;
    int g = (e0[k] >> 20) | ((e1[k] >> 20) << 2) | ((e2[k] >> 20) << 4);
    R = compose_map(g, R);
  }
}

extern "C" void kernel_launch(void* const* d_in, const int* in_sizes, int n_in,
                              void* d_out, int out_size, void* d_ws, size_t ws_size,
                              hipStream_t stream) {
  const float* logits = (const float*)d_in[0];
  float* lp = (float*)d_ws;
  int* idx = (int*)((char*)d_ws + (size_t)NB * NL * NT * sizeof(float));
  float* out = (float*)d_out;

  hipLaunchKernelGGL(k_rowtop5, dim3(NB * NL), dim3(256), 0, stream, logits, lp, idx);
  hipLaunchKernelGGL(k_beamscan, dim3(NB), dim3(64), 0, stream, lp, idx, out);
}